// Round 5
// baseline (919.136 us; speedup 1.0000x reference)
//
#include <hip/hip_runtime.h>
#include <hip/hip_bf16.h>
#include <math.h>

#define H 2048
#define IMOE 1408
#define NEXP 8
#define T_TOK 2048
#define ISH 2816
#define SCALEF 2.5f

#define NT_GU_R (IMOE / 64)   // 22
#define NT_GU_S (ISH / 64)    // 44
#define NT_DN   (H / 128)     // 16
#define XCAP_GU 224           // max tiles per XCD (worst case 214)
#define XCAP_DN 136           // worst case 128

typedef __attribute__((ext_vector_type(8))) short short8;
typedef __attribute__((ext_vector_type(4))) short short4v;
typedef __attribute__((ext_vector_type(4))) float floatx4;

union U8 { short8 s; unsigned u[4]; };

__device__ inline float b2f(short v) {
    unsigned int u = ((unsigned int)(unsigned short)v) << 16;
    float f; __builtin_memcpy(&f, &u, 4); return f;
}
__device__ inline short f2b(float f) {
    __hip_bfloat16 h = __float2bfloat16(f);
    short s; __builtin_memcpy(&s, &h, 2); return s;
}
__device__ __forceinline__ unsigned pkbf16(float a, float b) {
    float2 t; t.x = a; t.y = b;
    __hip_bfloat162 h2 = __float22bfloat162_rn(t);
    unsigned u; __builtin_memcpy(&u, &h2, 4); return u;
}
__device__ __forceinline__ void async16(const short* g, short* l) {
    __builtin_amdgcn_global_load_lds(
        (const __attribute__((address_space(1))) unsigned*)g,
        (__attribute__((address_space(3))) unsigned*)l, 16, 0, 0);
}

// ---------------- Router ----------------
__global__ __launch_bounds__(256) void router_kernel(
    const float* __restrict__ x, const float* __restrict__ rw,
    const float* __restrict__ bias,
    int* __restrict__ cnt, int* __restrict__ tokList, int* __restrict__ slotList,
    float* __restrict__ pairW)
{
    const int wid  = (blockIdx.x * 256 + threadIdx.x) >> 6;
    const int lane = threadIdx.x & 63;
    if (wid >= T_TOK) return;
    const float* xr = x + (size_t)wid * H;

    float acc[NEXP];
#pragma unroll
    for (int e = 0; e < NEXP; ++e) acc[e] = 0.f;

#pragma unroll
    for (int c = 0; c < 8; ++c) {
        int idx = (c * 64 + lane) * 4;
        floatx4 xv = *(const floatx4*)(xr + idx);
#pragma unroll
        for (int e = 0; e < NEXP; ++e) {
            floatx4 wv = *(const floatx4*)(rw + e * H + idx);
            acc[e] += xv.x * wv.x + xv.y * wv.y + xv.z * wv.z + xv.w * wv.w;
        }
    }
#pragma unroll
    for (int e = 0; e < NEXP; ++e)
        for (int off = 32; off; off >>= 1)
            acc[e] += __shfl_xor(acc[e], off, 64);

    if (lane == 0) {
        float s[NEXP], sfc[NEXP];
#pragma unroll
        for (int e = 0; e < NEXP; ++e) {
            s[e]   = 1.0f / (1.0f + expf(-acc[e]));
            sfc[e] = s[e] + bias[e];
        }
        float gs[4];
#pragma unroll
        for (int g = 0; g < 4; ++g) gs[g] = sfc[2 * g] + sfc[2 * g + 1];
        int g1 = 0;
        for (int g = 1; g < 4; ++g) if (gs[g] > gs[g1]) g1 = g;
        int g2 = -1;
        for (int g = 0; g < 4; ++g) {
            if (g == g1) continue;
            if (g2 < 0 || gs[g] > gs[g2]) g2 = g;
        }
        float msk[NEXP];
#pragma unroll
        for (int e = 0; e < NEXP; ++e) {
            int g = e >> 1;
            msk[e] = (g == g1 || g == g2) ? sfc[e] : 0.0f;
        }
        int e1 = 0;
        for (int e = 1; e < NEXP; ++e) if (msk[e] > msk[e1]) e1 = e;
        int e2 = -1;
        for (int e = 0; e < NEXP; ++e) {
            if (e == e1) continue;
            if (e2 < 0 || msk[e] > msk[e2]) e2 = e;
        }
        float w1 = s[e1], w2 = s[e2];
        float inv = SCALEF / (w1 + w2 + 1e-20f);
        w1 *= inv; w2 *= inv;
        int p1 = atomicAdd(&cnt[e1], 1);
        tokList[e1 * T_TOK + p1]  = wid;
        slotList[e1 * T_TOK + p1] = 2 * wid;
        pairW[2 * wid] = w1;
        int p2 = atomicAdd(&cnt[e2], 1);
        tokList[e2 * T_TOK + p2]  = wid;
        slotList[e2 * T_TOK + p2] = 2 * wid + 1;
        pairW[2 * wid + 1] = w2;
    }
}

// ---------------- Plan: counts -> row bases + per-XCD tile tables ----------------
// meta[0..8]: M per entry (8 = shared); meta[9..17]: compact row base;
// meta[44+c]: gu tiles on XCD c; meta[52+c]: dn tiles on XCD c.
__global__ void plan_kernel(const int* __restrict__ cnt, int* __restrict__ meta,
                            int* __restrict__ guTab, int* __restrict__ dnTab)
{
    if (threadIdx.x != 0 || blockIdx.x != 0) return;
    int base = 0;
    for (int e = 0; e < NEXP; ++e) {
        meta[e] = cnt[e];
        meta[9 + e] = base;
        base += cnt[e];
    }
    meta[8] = T_TOK;
    meta[17] = 0;
    int loadG[8] = {0,0,0,0,0,0,0,0};
    int loadD[8] = {0,0,0,0,0,0,0,0};
    for (int ent = 0; ent < 9; ++ent) {
        int M  = (ent < 8) ? cnt[ent] : T_TOK;
        int MT = (M + 127) >> 7;
        int NT = (ent < 8) ? NT_GU_R : NT_GU_S;
        for (int nt = 0; nt < NT; ++nt) {
            int c = 0;
            for (int j = 1; j < 8; ++j) if (loadG[j] < loadG[c]) c = j;
            for (int mt = 0; mt < MT; ++mt)
                guTab[c * XCAP_GU + loadG[c]++] = (ent << 16) | (nt << 8) | mt;
        }
        for (int nt = 0; nt < NT_DN; ++nt) {
            int c = 0;
            for (int j = 1; j < 8; ++j) if (loadD[j] < loadD[c]) c = j;
            for (int mt = 0; mt < MT; ++mt)
                dnTab[c * XCAP_DN + loadD[c]++] = (ent << 16) | (nt << 8) | mt;
        }
    }
    for (int c = 0; c < 8; ++c) { meta[44 + c] = loadG[c]; meta[52 + c] = loadD[c]; }
}

// ---------------- fp32 -> bf16 convert ----------------
__global__ __launch_bounds__(256) void convert_kernel(
    const float* __restrict__ src, short* __restrict__ dst, int n4)
{
    int idx = blockIdx.x * 256 + threadIdx.x;
    int stride = gridDim.x * 256;
    for (; idx < n4; idx += stride) {
        floatx4 v = *(const floatx4*)(src + (size_t)idx * 4);
        short4v o = { f2b(v.x), f2b(v.y), f2b(v.z), f2b(v.w) };
        *(short4v*)(dst + (size_t)idx * 4) = o;
    }
}

// ---------------- Fused gate+up grouped GEMM (XCD tile table) ----------------
// BM=128, BN=64 per matrix, BK=64, K=H. A bf16 gathered; B bf16 (async16) or fp32 (cvt).
__global__ __launch_bounds__(256) void gu_gemm(
    const short* __restrict__ xb,
    const short* __restrict__ gwb, const short* __restrict__ uwb,
    const float* __restrict__ gw, const float* __restrict__ uw,
    const short* __restrict__ sgwb, const short* __restrict__ suwb,
    const float* __restrict__ sgw, const float* __restrict__ suw,
    short* __restrict__ hiddenP, short* __restrict__ hiddenS,
    const int* __restrict__ tokList, const int* __restrict__ meta,
    const int* __restrict__ guTab)
{
    const int c8 = blockIdx.x & 7;
    const int ti = blockIdx.x >> 3;
    if (ti >= meta[44 + c8]) return;
    const int t = guTab[c8 * XCAP_GU + ti];
    const int e = t >> 16, nt = (t >> 8) & 255, mt = t & 255;

    int M, Nout, rowBase;
    const short *bg16, *bu16;
    const float *bg32, *bu32;
    const int* gat;
    short* outP;
    if (e < 8) {
        M = meta[e]; Nout = IMOE; rowBase = meta[9 + e];
        bg16 = gwb ? gwb + (size_t)e * IMOE * H : nullptr;
        bu16 = uwb ? uwb + (size_t)e * IMOE * H : nullptr;
        bg32 = gw + (size_t)e * IMOE * H;
        bu32 = uw + (size_t)e * IMOE * H;
        gat = tokList + e * T_TOK;
        outP = hiddenP;
    } else {
        M = T_TOK; Nout = ISH; rowBase = 0;
        bg16 = sgwb; bu16 = suwb; bg32 = sgw; bu32 = suw;
        gat = nullptr; outP = hiddenS;
    }
    const bool useB16 = (bg16 != nullptr);

    __shared__ short As[128 * 64];
    __shared__ short Bg[64 * 64];
    __shared__ short Bu[64 * 64];

    const int tid  = threadIdx.x;
    const int w    = tid >> 6;
    const int lane = tid & 63;
    const int quad = lane >> 4;
    const int l16  = lane & 15;
    const int wm = w >> 1, wn = w & 1;

    const int r8 = lane >> 3;
    const int cs = (lane & 7) ^ r8;     // swizzled source chunk; phys chunk = lane&7

    const short* aSrc[4];
    short* ldsA[4];
#pragma unroll
    for (int i = 0; i < 4; ++i) {
        int r = w * 32 + i * 8 + r8;
        int p = mt * 128 + r;
        int pos = p < M ? p : (M - 1);
        int arow = gat ? gat[pos] : pos;
        aSrc[i] = xb + (size_t)arow * H + cs * 8;
        ldsA[i] = As + (w * 32 + i * 8) * 64;
    }

    floatx4 accg[4][2] = {};
    floatx4 accu[4][2] = {};

    auto mfma_step = [&]() {
        const int sw = l16 & 7;
        short8 af[4], bgf[2], buf[2];
#pragma unroll
        for (int kk2 = 0; kk2 < 2; ++kk2) {
            const int cc = kk2 * 4 + quad;
#pragma unroll
            for (int m = 0; m < 4; ++m)
                af[m] = *(const short8*)(As + (wm * 64 + m * 16 + l16) * 64 + (cc ^ sw) * 8);
#pragma unroll
            for (int n = 0; n < 2; ++n) {
                bgf[n] = *(const short8*)(Bg + (wn * 32 + n * 16 + l16) * 64 + (cc ^ sw) * 8);
                buf[n] = *(const short8*)(Bu + (wn * 32 + n * 16 + l16) * 64 + (cc ^ sw) * 8);
            }
#pragma unroll
            for (int m = 0; m < 4; ++m)
#pragma unroll
                for (int n = 0; n < 2; ++n) {
                    accg[m][n] = __builtin_amdgcn_mfma_f32_16x16x32_bf16(af[m], bgf[n], accg[m][n], 0, 0, 0);
                    accu[m][n] = __builtin_amdgcn_mfma_f32_16x16x32_bf16(af[m], buf[n], accu[m][n], 0, 0, 0);
                }
        }
    };

    if (useB16) {
        const short* bgSrc[2];
        const short* buSrc[2];
        short* ldsBg[2];
        short* ldsBu[2];
#pragma unroll
        for (int i = 0; i < 2; ++i) {
            int r = w * 16 + i * 8 + r8;
            bgSrc[i] = bg16 + (size_t)(nt * 64 + r) * H + cs * 8;
            buSrc[i] = bu16 + (size_t)(nt * 64 + r) * H + cs * 8;
            ldsBg[i] = Bg + (w * 16 + i * 8) * 64;
            ldsBu[i] = Bu + (w * 16 + i * 8) * 64;
        }
        for (int k0 = 0; k0 < H; k0 += 64) {
#pragma unroll
            for (int i = 0; i < 4; ++i) async16(aSrc[i] + k0, ldsA[i]);
#pragma unroll
            for (int i = 0; i < 2; ++i) {
                async16(bgSrc[i] + k0, ldsBg[i]);
                async16(buSrc[i] + k0, ldsBu[i]);
            }
            __syncthreads();
            mfma_step();
            __syncthreads();
        }
    } else {
        const int br = tid >> 2;
        const int bj = tid & 3;
        const int bs = br & 7;
        const float* b1p = bg32 + (size_t)(nt * 64 + br) * H + bj * 16;
        const float* b2p = bu32 + (size_t)(nt * 64 + br) * H + bj * 16;
        short* bgDst0 = Bg + br * 64 + (((2 * bj)    ) ^ bs) * 8;
        short* bgDst1 = Bg + br * 64 + (((2 * bj) + 1) ^ bs) * 8;
        short* buDst0 = Bu + br * 64 + (((2 * bj)    ) ^ bs) * 8;
        short* buDst1 = Bu + br * 64 + (((2 * bj) + 1) ^ bs) * 8;
        for (int k0 = 0; k0 < H; k0 += 64) {
#pragma unroll
            for (int i = 0; i < 4; ++i) async16(aSrc[i] + k0, ldsA[i]);
            {
                floatx4 v0 = ((const floatx4*)(b1p + k0))[0];
                floatx4 v1 = ((const floatx4*)(b1p + k0))[1];
                floatx4 v2 = ((const floatx4*)(b1p + k0))[2];
                floatx4 v3 = ((const floatx4*)(b1p + k0))[3];
                U8 lo, hi;
                lo.u[0] = pkbf16(v0.x, v0.y); lo.u[1] = pkbf16(v0.z, v0.w);
                lo.u[2] = pkbf16(v1.x, v1.y); lo.u[3] = pkbf16(v1.z, v1.w);
                hi.u[0] = pkbf16(v2.x, v2.y); hi.u[1] = pkbf16(v2.z, v2.w);
                hi.u[2] = pkbf16(v3.x, v3.y); hi.u[3] = pkbf16(v3.z, v3.w);
                *(short8*)bgDst0 = lo.s;
                *(short8*)bgDst1 = hi.s;
            }
            {
                floatx4 v0 = ((const floatx4*)(b2p + k0))[0];
                floatx4 v1 = ((const floatx4*)(b2p + k0))[1];
                floatx4 v2 = ((const floatx4*)(b2p + k0))[2];
                floatx4 v3 = ((const floatx4*)(b2p + k0))[3];
                U8 lo, hi;
                lo.u[0] = pkbf16(v0.x, v0.y); lo.u[1] = pkbf16(v0.z, v0.w);
                lo.u[2] = pkbf16(v1.x, v1.y); lo.u[3] = pkbf16(v1.z, v1.w);
                hi.u[0] = pkbf16(v2.x, v2.y); hi.u[1] = pkbf16(v2.z, v2.w);
                hi.u[2] = pkbf16(v3.x, v3.y); hi.u[3] = pkbf16(v3.z, v3.w);
                *(short8*)buDst0 = lo.s;
                *(short8*)buDst1 = hi.s;
            }
            __syncthreads();
            mfma_step();
            __syncthreads();
        }
    }

#pragma unroll
    for (int m = 0; m < 4; ++m) {
#pragma unroll
        for (int rr = 0; rr < 4; ++rr) {
            int lr = wm * 64 + m * 16 + quad * 4 + rr;
            int p = mt * 128 + lr;
            if (p >= M) continue;
            size_t rowoff = (size_t)(rowBase + p) * Nout + nt * 64 + wn * 32;
#pragma unroll
            for (int n = 0; n < 2; ++n) {
                float g = accg[m][n][rr];
                float u = accu[m][n][rr];
                outP[rowoff + n * 16 + l16] = f2b(g / (1.0f + __expf(-g)) * u);
            }
        }
    }
}

// ---------------- Down grouped GEMM (XCD tile table) ----------------
// BM=128, BN=128, BK=64. A = compact hidden (bf16); B bf16 (async16) or fp32 (cvt).
__global__ __launch_bounds__(256) void dn_gemm(
    const short* __restrict__ hiddenP, const short* __restrict__ hiddenS,
    const short* __restrict__ dwb, const short* __restrict__ sdwb,
    const float* __restrict__ dw, const float* __restrict__ sdw,
    short* __restrict__ outPairs, short* __restrict__ sharedOut,
    const int* __restrict__ slotList, const int* __restrict__ meta,
    const int* __restrict__ dnTab)
{
    const int c8 = blockIdx.x & 7;
    const int ti = blockIdx.x >> 3;
    if (ti >= meta[52 + c8]) return;
    const int t = dnTab[c8 * XCAP_DN + ti];
    const int e = t >> 16, nt = (t >> 8) & 255, mt = t & 255;

    int M, K, rowBase;
    const short* b16;
    const float* b32;
    const short* Abase;
    const int* scat;
    short* outP;
    if (e < 8) {
        M = meta[e]; K = IMOE; rowBase = meta[9 + e];
        b16 = dwb ? dwb + (size_t)e * H * IMOE : nullptr;
        b32 = dw + (size_t)e * H * IMOE;
        Abase = hiddenP; scat = slotList + e * T_TOK; outP = outPairs;
    } else {
        M = T_TOK; K = ISH; rowBase = 0;
        b16 = sdwb; b32 = sdw;
        Abase = hiddenS; scat = nullptr; outP = sharedOut;
    }
    const bool useB16 = (b16 != nullptr);

    __shared__ short As[128 * 64];
    __shared__ short Bs[128 * 64];

    const int tid  = threadIdx.x;
    const int w    = tid >> 6;
    const int lane = tid & 63;
    const int quad = lane >> 4;
    const int l16  = lane & 15;
    const int wm = w >> 1, wn = w & 1;

    const int r8 = lane >> 3;
    const int cs = (lane & 7) ^ r8;

    const short* aSrc[4];
    short* ldsA[4];
#pragma unroll
    for (int i = 0; i < 4; ++i) {
        int r = w * 32 + i * 8 + r8;
        int p = mt * 128 + r;
        int pos = p < M ? p : (M - 1);
        aSrc[i] = Abase + (size_t)(rowBase + pos) * K + cs * 8;
        ldsA[i] = As + (w * 32 + i * 8) * 64;
    }

    floatx4 acc[4][4] = {};

    auto mfma_step = [&]() {
        const int sw = l16 & 7;
        short8 af[4], bf[4];
#pragma unroll
        for (int kk2 = 0; kk2 < 2; ++kk2) {
            const int cc = kk2 * 4 + quad;
#pragma unroll
            for (int m = 0; m < 4; ++m)
                af[m] = *(const short8*)(As + (wm * 64 + m * 16 + l16) * 64 + (cc ^ sw) * 8);
#pragma unroll
            for (int n = 0; n < 4; ++n)
                bf[n] = *(const short8*)(Bs + (wn * 64 + n * 16 + l16) * 64 + (cc ^ sw) * 8);
#pragma unroll
            for (int m = 0; m < 4; ++m)
#pragma unroll
                for (int n = 0; n < 4; ++n)
                    acc[m][n] = __builtin_amdgcn_mfma_f32_16x16x32_bf16(af[m], bf[n], acc[m][n], 0, 0, 0);
        }
    };

    if (useB16) {
        const short* bSrc[4];
        short* ldsB[4];
#pragma unroll
        for (int i = 0; i < 4; ++i) {
            int r = w * 32 + i * 8 + r8;
            bSrc[i] = b16 + (size_t)(nt * 128 + r) * K + cs * 8;
            ldsB[i] = Bs + (w * 32 + i * 8) * 64;
        }
        for (int k0 = 0; k0 < K; k0 += 64) {
#pragma unroll
            for (int i = 0; i < 4; ++i) async16(aSrc[i] + k0, ldsA[i]);
#pragma unroll
            for (int i = 0; i < 4; ++i) async16(bSrc[i] + k0, ldsB[i]);
            __syncthreads();
            mfma_step();
            __syncthreads();
        }
    } else {
        const int br = tid >> 1;
        const int bh = tid & 1;
        const int bs = br & 7;
        const float* bpp = b32 + (size_t)(nt * 128 + br) * K + bh * 32;
        short* bDst[4];
#pragma unroll
        for (int i = 0; i < 4; ++i)
            bDst[i] = Bs + br * 64 + ((bh * 4 + i) ^ bs) * 8;
        for (int k0 = 0; k0 < K; k0 += 64) {
#pragma unroll
            for (int i = 0; i < 4; ++i) async16(aSrc[i] + k0, ldsA[i]);
#pragma unroll
            for (int i = 0; i < 4; ++i) {
                floatx4 v0 = ((const floatx4*)(bpp + k0))[2 * i];
                floatx4 v1 = ((const floatx4*)(bpp + k0))[2 * i + 1];
                U8 cv;
                cv.u[0] = pkbf16(v0.x, v0.y); cv.u[1] = pkbf16(v0.z, v0.w);
                cv.u[2] = pkbf16(v1.x, v1.y); cv.u[3] = pkbf16(v1.z, v1.w);
                *(short8*)bDst[i] = cv.s;
            }
            __syncthreads();
            mfma_step();
            __syncthreads();
        }
    }

#pragma unroll
    for (int m = 0; m < 4; ++m) {
#pragma unroll
        for (int rr = 0; rr < 4; ++rr) {
            int lr = wm * 64 + m * 16 + quad * 4 + rr;
            int p = mt * 128 + lr;
            if (p >= M) continue;
            int crow = scat ? scat[p] : p;
            size_t rowoff = (size_t)crow * H + nt * 128 + wn * 64;
#pragma unroll
            for (int n = 0; n < 4; ++n)
                outP[rowoff + n * 16 + l16] = f2b(acc[m][n][rr]);
        }
    }
}

// ---------------- Combine ----------------
__global__ __launch_bounds__(256) void combine_kernel(
    const short* __restrict__ outPairs, const short* __restrict__ sharedOut,
    const float* __restrict__ pairW, float* __restrict__ out)
{
    size_t gi = ((size_t)blockIdx.x * 256 + threadIdx.x) * 8;
    int t = (int)(gi >> 11);
    int h = (int)(gi & (H - 1));
    float w0 = pairW[2 * t], w1 = pairW[2 * t + 1];
    short8 p0 = *(const short8*)(outPairs + (size_t)(2 * t) * H + h);
    short8 p1 = *(const short8*)(outPairs + (size_t)(2 * t + 1) * H + h);
    short8 sh = *(const short8*)(sharedOut + gi);
    floatx4 o0, o1;
#pragma unroll
    for (int j = 0; j < 4; ++j)
        o0[j] = w0 * b2f(p0[j]) + w1 * b2f(p1[j]) + b2f(sh[j]);
#pragma unroll
    for (int j = 0; j < 4; ++j)
        o1[j] = w0 * b2f(p0[4 + j]) + w1 * b2f(p1[4 + j]) + b2f(sh[4 + j]);
    *(floatx4*)(out + gi)     = o0;
    *(floatx4*)(out + gi + 4) = o1;
}

extern "C" void kernel_launch(void* const* d_in, const int* in_sizes, int n_in,
                              void* d_out, int out_size, void* d_ws, size_t ws_size,
                              hipStream_t stream)
{
    const float* x    = (const float*)d_in[0];
    const float* rw   = (const float*)d_in[1];
    const float* bias = (const float*)d_in[2];
    const float* gw   = (const float*)d_in[3];
    const float* uw   = (const float*)d_in[4];
    const float* dw   = (const float*)d_in[5];
    const float* sgw  = (const float*)d_in[6];
    const float* suw  = (const float*)d_in[7];
    const float* sdw  = (const float*)d_in[8];
    float* out = (float*)d_out;

    char* ws = (char*)d_ws;
    size_t off = 0;
    auto alloc = [&](size_t bytes) {
        off = (off + 255) & ~(size_t)255;
        void* p = ws + off;
        off += bytes;
        return p;
    };
    int*   cnt      = (int*)  alloc(NEXP * sizeof(int));
    int*   tokList  = (int*)  alloc((size_t)NEXP * T_TOK * sizeof(int));
    int*   slotList = (int*)  alloc((size_t)NEXP * T_TOK * sizeof(int));
    float* pairW    = (float*)alloc((size_t)2 * T_TOK * sizeof(float));
    int*   meta     = (int*)  alloc(64 * sizeof(int));
    int*   guTab    = (int*)  alloc((size_t)8 * XCAP_GU * sizeof(int));
    int*   dnTab    = (int*)  alloc((size_t)8 * XCAP_DN * sizeof(int));
    short* xb       = (short*)alloc((size_t)T_TOK * H * sizeof(short));
    short* hiddenP  = (short*)alloc((size_t)2 * T_TOK * IMOE * sizeof(short));
    short* hiddenS  = (short*)alloc((size_t)T_TOK * ISH * sizeof(short));
    // tier arenas
    short* A1 = (short*)alloc((size_t)NEXP * IMOE * H * sizeof(short));  // gw-bf16, then dw-bf16
    short* A2 = (short*)alloc((size_t)NEXP * IMOE * H * sizeof(short));  // uw-bf16; outPairs/sharedOut alias after gu
    size_t off_tierR = off;
    short* A3 = (short*)alloc((size_t)ISH * H * sizeof(short));          // sgw-bf16, then sdw-bf16
    short* A4 = (short*)alloc((size_t)ISH * H * sizeof(short));          // suw-bf16
    size_t off_tierS = off;

    int tier = (ws_size >= off_tierS) ? 2 : (ws_size >= off_tierR) ? 1 : 0;

    // outPairs/sharedOut: alias onto a dead weight arena
    short* outPairs  = (tier >= 1) ? A2 : A1;                 // 4096*H shorts
    short* sharedOut = outPairs + (size_t)2 * T_TOK * H;      // T_TOK*H shorts

    hipMemsetAsync(cnt, 0, NEXP * sizeof(int), stream);
    router_kernel<<<T_TOK / 4, 256, 0, stream>>>(x, rw, bias, cnt, tokList, slotList, pairW);
    plan_kernel<<<1, 64, 0, stream>>>(cnt, meta, guTab, dnTab);
    convert_kernel<<<2048, 256, 0, stream>>>(x, xb, T_TOK * H / 4);

    if (tier >= 1) {
        convert_kernel<<<2048, 256, 0, stream>>>(gw, A1, NEXP * IMOE * H / 4);
        convert_kernel<<<2048, 256, 0, stream>>>(uw, A2, NEXP * IMOE * H / 4);
    }
    if (tier >= 2) {
        convert_kernel<<<2048, 256, 0, stream>>>(sgw, A3, ISH * H / 4);
        convert_kernel<<<2048, 256, 0, stream>>>(suw, A4, ISH * H / 4);
    }

    gu_gemm<<<8 * XCAP_GU, 256, 0, stream>>>(
        xb,
        (tier >= 1) ? A1 : nullptr, (tier >= 1) ? A2 : nullptr, gw, uw,
        (tier >= 2) ? A3 : nullptr, (tier >= 2) ? A4 : nullptr, sgw, suw,
        hiddenP, hiddenS, tokList, meta, guTab);

    if (tier >= 1)
        convert_kernel<<<2048, 256, 0, stream>>>(dw, A1, NEXP * H * IMOE / 4);
    if (tier >= 2)
        convert_kernel<<<2048, 256, 0, stream>>>(sdw, A3, H * ISH / 4);

    dn_gemm<<<8 * XCAP_DN, 256, 0, stream>>>(
        hiddenP, hiddenS,
        (tier >= 1) ? A1 : nullptr, (tier >= 2) ? A3 : nullptr, dw, sdw,
        outPairs, sharedOut, slotList, meta, dnTab);

    combine_kernel<<<(T_TOK * H / 8) / 256, 256, 0, stream>>>(outPairs, sharedOut, pairW, out);
}